// Round 1
// baseline (3704.263 us; speedup 1.0000x reference)
//
#include <hip/hip_runtime.h>
#include <hip/hip_fp16.h>

// Problem constants
#define Bsz 4096
#define Tt  336
#define Fin 12
#define Hh  50
#define Gg  200   // 4*H
#define BT  16    // batch rows per block
#define NTHREADS 256

typedef _Float16 half8 __attribute__((ext_vector_type(8)));

// LDS plan (~142.6 KiB of 160 KiB):
//  w0: layer0 weights [jc=8][g=200][8] fp16   (j = [x(12) | h0(50) | pad2])
//  w1/w2: [jc=13][g=200][8] fp16              (j = [h_prev(50) | h_self(50) | pad4])
//  in0: [parity][r=16][64]  = [x_t | h0 | pad]  fp32
//  in1: [parity][r=16][104] = [h0 | h1 | pad]
//  in2: [parity][r=16][104] = [h1 | h2 | pad]
struct __align__(16) SMem {
  _Float16 w0[8  * Gg * 8];
  _Float16 w1[13 * Gg * 8];
  _Float16 w2[13 * Gg * 8];
  float bias[3][Gg];
  float in0[2][BT][64];
  float in1[2][BT][104];
  float in2[2][BT][104];
};

__device__ __forceinline__ float fsig(float x) {
  return __builtin_amdgcn_rcpf(1.f + __builtin_amdgcn_exp2f(-1.442695041f * x));
}
__device__ __forceinline__ float ftanh(float x) {
  // tanh(x) = 1 - 2/(1+e^{2x}); saturates correctly at +-inf
  return 1.f - 2.f * __builtin_amdgcn_rcpf(1.f + __builtin_amdgcn_exp2f(2.885390082f * x));
}

// Accumulate 4 gate pre-activations for 4 rows.
// wsw: swizzled fp16 weights [jc][200][8]; inb: [BT][RL] fp32 input vectors.
template<int NC, int RL>
__device__ __forceinline__ void gate_accum(const _Float16* wsw,
                                           const float (*inb)[RL],
                                           int r0, int u, float z[4][4]) {
  const half8* w8 = (const half8*)wsw;
#pragma unroll 2
  for (int jc = 0; jc < NC; ++jc) {
    half8 wA = w8[jc * Gg + u];            // gate i row
    half8 wB = w8[jc * Gg + u + Hh];       // gate f row
    half8 wC = w8[jc * Gg + u + 2 * Hh];   // gate g row
    half8 wD = w8[jc * Gg + u + 3 * Hh];   // gate o row
    float wa[8], wb[8], wc[8], wd[8];
#pragma unroll
    for (int k = 0; k < 8; ++k) {
      wa[k] = (float)wA[k]; wb[k] = (float)wB[k];
      wc[k] = (float)wC[k]; wd[k] = (float)wD[k];
    }
#pragma unroll
    for (int ri = 0; ri < 4; ++ri) {
      const float4* ap = (const float4*)&inb[r0 + ri][jc * 8];  // wave-uniform broadcast
      float4 lo = ap[0], hi = ap[1];
      float a[8] = {lo.x, lo.y, lo.z, lo.w, hi.x, hi.y, hi.z, hi.w};
#pragma unroll
      for (int k = 0; k < 8; ++k) {
        z[0][ri] += wa[k] * a[k];
        z[1][ri] += wb[k] * a[k];
        z[2][ri] += wc[k] * a[k];
        z[3][ri] += wd[k] * a[k];
      }
    }
  }
}

__global__ __launch_bounds__(NTHREADS, 1)
void lstm_fused_kernel(const float* __restrict__ x,
                       const float* __restrict__ Wih0, const float* __restrict__ Whh0,
                       const float* __restrict__ bih0, const float* __restrict__ bhh0,
                       const float* __restrict__ Wih1, const float* __restrict__ Whh1,
                       const float* __restrict__ bih1, const float* __restrict__ bhh1,
                       const float* __restrict__ Wih2, const float* __restrict__ Whh2,
                       const float* __restrict__ bih2, const float* __restrict__ bhh2,
                       const float* __restrict__ Wlin, const float* __restrict__ blin,
                       float* __restrict__ out) {
  __shared__ SMem sm;
  const int tid = threadIdx.x;
  const int blk = blockIdx.x;

  // ---- stage weights into LDS (fp32 -> fp16, swizzled [jc][g][8]) ----
  for (int idx = tid; idx < 8 * Gg * 8; idx += NTHREADS) {
    int k = idx & 7;
    int g = (idx >> 3) % Gg;
    int jc = idx / (8 * Gg);
    int j = jc * 8 + k;
    float v = 0.f;
    if (j < Fin)            v = Wih0[g * Fin + j];
    else if (j < Fin + Hh)  v = Whh0[g * Hh + (j - Fin)];
    sm.w0[idx] = (_Float16)v;
  }
  for (int idx = tid; idx < 13 * Gg * 8; idx += NTHREADS) {
    int k = idx & 7;
    int g = (idx >> 3) % Gg;
    int jc = idx / (8 * Gg);
    int j = jc * 8 + k;
    float v1 = 0.f, v2 = 0.f;
    if (j < Hh)          { v1 = Wih1[g * Hh + j];        v2 = Wih2[g * Hh + j]; }
    else if (j < 2 * Hh) { v1 = Whh1[g * Hh + (j - Hh)]; v2 = Whh2[g * Hh + (j - Hh)]; }
    sm.w1[idx] = (_Float16)v1;
    sm.w2[idx] = (_Float16)v2;
  }
  for (int idx = tid; idx < 3 * Gg; idx += NTHREADS) {
    int l = idx / Gg, g = idx % Gg;
    const float* bi = (l == 0) ? bih0 : ((l == 1) ? bih1 : bih2);
    const float* bh = (l == 0) ? bhh0 : ((l == 1) ? bhh1 : bhh2);
    sm.bias[l][g] = bi[g] + bh[g];
  }
  // zero in-buffers (h_{-1} = 0 and pads)
  {
    float* zp = (float*)sm.in0;
    const int ZN = 2 * BT * 64 + 2 * 2 * BT * 104;
    for (int idx = tid; idx < ZN; idx += NTHREADS) zp[idx] = 0.f;
  }
  // stage x_0
  if (tid < BT * Fin) {
    int r = tid / Fin, f = tid % Fin;
    sm.in0[0][r][f] = x[(size_t)(blk * BT + r) * (Tt * Fin) + f];
  }
  __syncthreads();

  const int u  = tid & 63;    // hidden unit (active if < 50)
  const int rq = tid >> 6;    // wave id -> row quad
  const int r0 = rq * 4;
  const bool act = (u < Hh);
  const int xr = tid / Fin, xf = tid - (tid / Fin) * Fin;  // x staging coords (tid<192)

  float c0[4] = {0.f, 0.f, 0.f, 0.f};
  float c1[4] = {0.f, 0.f, 0.f, 0.f};
  float c2[4] = {0.f, 0.f, 0.f, 0.f};

  for (int t = 0; t < Tt; ++t) {
    const int p = t & 1;

    // prefetch x_{t+1} into registers (hidden under layer0 compute)
    float xreg = 0.f;
    if (tid < BT * Fin && (t + 1) < Tt)
      xreg = x[(size_t)(blk * BT + xr) * (Tt * Fin) + (t + 1) * Fin + xf];

    // ---------------- layer 0 ----------------
    if (act) {
      float z[4][4];
#pragma unroll
      for (int gi = 0; gi < 4; ++gi) {
        float bv = sm.bias[0][u + Hh * gi];
#pragma unroll
        for (int ri = 0; ri < 4; ++ri) z[gi][ri] = bv;
      }
      gate_accum<8, 64>(sm.w0, sm.in0[p], r0, u, z);
#pragma unroll
      for (int ri = 0; ri < 4; ++ri) {
        float ig = fsig(z[0][ri]), fg = fsig(z[1][ri]);
        float gg = ftanh(z[2][ri]), og = fsig(z[3][ri]);
        float c = fg * c0[ri] + ig * gg;
        c0[ri] = c;
        float h = og * ftanh(c);
        sm.in0[1 - p][r0 + ri][Fin + u] = h;  // recurrent input for t+1
        sm.in1[p][r0 + ri][u] = h;            // feed layer 1 this step
      }
    }
    if (tid < BT * Fin) sm.in0[1 - p][xr][xf] = xreg;  // x_{t+1}
    __syncthreads();

    // ---------------- layer 1 ----------------
    if (act) {
      float z[4][4];
#pragma unroll
      for (int gi = 0; gi < 4; ++gi) {
        float bv = sm.bias[1][u + Hh * gi];
#pragma unroll
        for (int ri = 0; ri < 4; ++ri) z[gi][ri] = bv;
      }
      gate_accum<13, 104>(sm.w1, sm.in1[p], r0, u, z);
#pragma unroll
      for (int ri = 0; ri < 4; ++ri) {
        float ig = fsig(z[0][ri]), fg = fsig(z[1][ri]);
        float gg = ftanh(z[2][ri]), og = fsig(z[3][ri]);
        float c = fg * c1[ri] + ig * gg;
        c1[ri] = c;
        float h = og * ftanh(c);
        sm.in1[1 - p][r0 + ri][Hh + u] = h;   // recurrent for t+1
        sm.in2[p][r0 + ri][u] = h;            // feed layer 2 this step
      }
    }
    __syncthreads();

    // ---------------- layer 2 ----------------
    if (act) {
      float z[4][4];
#pragma unroll
      for (int gi = 0; gi < 4; ++gi) {
        float bv = sm.bias[2][u + Hh * gi];
#pragma unroll
        for (int ri = 0; ri < 4; ++ri) z[gi][ri] = bv;
      }
      gate_accum<13, 104>(sm.w2, sm.in2[p], r0, u, z);
#pragma unroll
      for (int ri = 0; ri < 4; ++ri) {
        float ig = fsig(z[0][ri]), fg = fsig(z[1][ri]);
        float gg = ftanh(z[2][ri]), og = fsig(z[3][ri]);
        float c = fg * c2[ri] + ig * gg;
        c2[ri] = c;
        float h = og * ftanh(c);
        sm.in2[1 - p][r0 + ri][Hh + u] = h;   // recurrent for t+1 (and final output)
      }
    }
    __syncthreads();
  }

  // ---- epilogue: out[r] = b_lin + h2_{T-1} . W_lin ----
  // final h2 lives in in2[T&1 == 0][r][Hh..Hh+49]
  if (tid < BT) {
    float s = blin[0];
    for (int uu = 0; uu < Hh; ++uu)
      s += Wlin[uu] * sm.in2[0][tid][Hh + uu];
    out[blk * BT + tid] = s;
  }
}

extern "C" void kernel_launch(void* const* d_in, const int* in_sizes, int n_in,
                              void* d_out, int out_size, void* d_ws, size_t ws_size,
                              hipStream_t stream) {
  const float* x    = (const float*)d_in[0];
  const float* Wih0 = (const float*)d_in[1];
  const float* Whh0 = (const float*)d_in[2];
  const float* bih0 = (const float*)d_in[3];
  const float* bhh0 = (const float*)d_in[4];
  const float* Wih1 = (const float*)d_in[5];
  const float* Whh1 = (const float*)d_in[6];
  const float* bih1 = (const float*)d_in[7];
  const float* bhh1 = (const float*)d_in[8];
  const float* Wih2 = (const float*)d_in[9];
  const float* Whh2 = (const float*)d_in[10];
  const float* bih2 = (const float*)d_in[11];
  const float* bhh2 = (const float*)d_in[12];
  const float* Wlin = (const float*)d_in[13];
  const float* blin = (const float*)d_in[14];
  float* out = (float*)d_out;

  dim3 grid(Bsz / BT);   // 256 blocks, one per CU
  dim3 block(NTHREADS);  // 4 waves
  lstm_fused_kernel<<<grid, block, 0, stream>>>(
      x, Wih0, Whh0, bih0, bhh0, Wih1, Whh1, bih1, bhh1,
      Wih2, Whh2, bih2, bhh2, Wlin, blin, out);
}

// Round 2
// 838.463 us; speedup vs baseline: 4.4179x; 4.4179x over previous
//
#include <hip/hip_runtime.h>
#include <hip/hip_fp16.h>

// Problem: 3-layer LSTM, B=4096, T=336, F=12, H=50, fp32 in/out.
// Strategy: per-CU batch tile of 16 rows; z^T = W'(gate-permuted) @ a^T via
// mfma_f32_16x16x32_f16. Permutation row' = 4*unit + gate makes each lane's
// 4 accumulators = the 4 gates of one unit -> lane-local c/h update, c in
// registers for all 336 steps. Weights live in VGPRs (loaded once).
// Activation planes in LDS, parity double-buffered -> 2 barriers/step.

#define Bsz 4096
#define Tt  336
#define BT  16
#define NTH 256

typedef _Float16 half8 __attribute__((ext_vector_type(8)));
typedef float    floatx4 __attribute__((ext_vector_type(4)));

// LDS activation planes (halfs). Row strides chosen 16B-aligned.
#define S0  80    // act0: [x(12) | h0(50) | pad], k-reads cover 0..63
#define S12 144   // act1/act2: [h_in(50) | h_self(50) | pad], k-reads cover 0..127

struct __align__(16) SMem {
  _Float16 act0[2][BT][S0];    // [parity][batch][k]
  _Float16 act1[2][BT][S12];
  _Float16 act2[2][BT][S12];
};  // 23552 B

__device__ __forceinline__ float fsig(float x) {
  return __builtin_amdgcn_rcpf(1.f + __builtin_amdgcn_exp2f(-1.442695041f * x));
}
__device__ __forceinline__ float ftanh(float x) {
  return 1.f - 2.f * __builtin_amdgcn_rcpf(1.f + __builtin_amdgcn_exp2f(2.885390082f * x));
}

// Load one A-operand fragment (8 halfs) of the gate-permuted weight matrix.
// Permuted row R = 4*u + g ; source row in W_ih/W_hh is g*50+u.
// k < bound -> W_ih[row][k] (row length lenih); bound <= k < bound+50 -> W_hh[row][k-bound].
__device__ __forceinline__ half8 wfrag(const float* __restrict__ Wih,
                                       const float* __restrict__ Whh,
                                       int lenih, int bound, int R, int k0) {
  half8 r = {};
  int u = R >> 2, g = R & 3;
  if (u < 50) {
    int row = g * 50 + u;
#pragma unroll
    for (int j = 0; j < 8; ++j) {
      int k = k0 + j;
      float v = 0.f;
      if (k < bound)           v = Wih[row * lenih + k];
      else if (k < bound + 50) v = Whh[row * 50 + (k - bound)];
      r[j] = (_Float16)v;
    }
  }
  return r;
}

__global__ __launch_bounds__(NTH, 1)
void lstm_mfma_kernel(const float* __restrict__ x,
                      const float* __restrict__ Wih0, const float* __restrict__ Whh0,
                      const float* __restrict__ bih0, const float* __restrict__ bhh0,
                      const float* __restrict__ Wih1, const float* __restrict__ Whh1,
                      const float* __restrict__ bih1, const float* __restrict__ bhh1,
                      const float* __restrict__ Wih2, const float* __restrict__ Whh2,
                      const float* __restrict__ bih2, const float* __restrict__ bhh2,
                      const float* __restrict__ Wlin, const float* __restrict__ blin,
                      float* __restrict__ out) {
  __shared__ SMem sm;
  const int tid  = threadIdx.x;
  const int blk  = blockIdx.x;
  const int lane = tid & 63;
  const int w    = tid >> 6;      // wave id 0..3
  const int n    = lane & 15;     // batch col (B/D) and A-row within tile
  const int q    = lane >> 4;     // quad -> k-group / D row-group

  // ---- zero LDS (h(-1)=0 and all pads) ----
  {
    int* zp = (int*)&sm;
    for (int i = tid; i < (int)(sizeof(SMem) / 4); i += NTH) zp[i] = 0;
  }
  __syncthreads();

  // ---- load weight fragments + biases into registers (once) ----
  // wave w owns M-tiles m = w + 4*i (valid while m < 13); tile m covers units 4m..4m+3
  half8 a0[4][2], a1[4][4], a2[4][4];
  floatx4 bia0[4], bia1[4], bia2[4];
#pragma unroll
  for (int i = 0; i < 4; ++i) {
    int m = w + 4 * i;
    bool val = (m < 13);
    int mm = val ? m : 0;
    int R = 16 * mm + n;           // A-frag row = lane&15 within tile
#pragma unroll
    for (int kc = 0; kc < 2; ++kc)
      a0[i][kc] = val ? wfrag(Wih0, Whh0, 12, 12, R, kc * 32 + q * 8) : (half8){};
#pragma unroll
    for (int kc = 0; kc < 4; ++kc) {
      a1[i][kc] = val ? wfrag(Wih1, Whh1, 50, 50, R, kc * 32 + q * 8) : (half8){};
      a2[i][kc] = val ? wfrag(Wih2, Whh2, 50, 50, R, kc * 32 + q * 8) : (half8){};
    }
    floatx4 b0v = {0,0,0,0}, b1v = {0,0,0,0}, b2v = {0,0,0,0};
    int u = 4 * mm + q;            // D rows: unit = 4m+q, gate = reg
    if (val && u < 50) {
#pragma unroll
      for (int g = 0; g < 4; ++g) {
        b0v[g] = bih0[g * 50 + u] + bhh0[g * 50 + u];
        b1v[g] = bih1[g * 50 + u] + bhh1[g * 50 + u];
        b2v[g] = bih2[g * 50 + u] + bhh2[g * 50 + u];
      }
    }
    bia0[i] = b0v; bia1[i] = b1v; bia2[i] = b2v;
  }

  float c0[4] = {0,0,0,0}, c1[4] = {0,0,0,0}, c2[4] = {0,0,0,0};

  // ---- stage x(0), prefetch x(1) ----
  const int xr = tid / 12, xf = tid - (tid / 12) * 12;   // tid < 192
  float xnext = 0.f;
  if (tid < 192) {
    sm.act0[0][xr][xf] = (_Float16)x[((size_t)(blk * BT + xr) * Tt + 0) * 12 + xf];
    xnext = x[((size_t)(blk * BT + xr) * Tt + 1) * 12 + xf];
  }
  __syncthreads();

  for (int t = 0; t < Tt; ++t) {
    const int p = t & 1;

    // ================= layer 0 =================
    half8 b0f[2];
#pragma unroll
    for (int kc = 0; kc < 2; ++kc)
      b0f[kc] = *(const half8*)&sm.act0[p][n][kc * 32 + q * 8];
    floatx4 z[4];
#pragma unroll
    for (int i = 0; i < 4; ++i) {
      int m = w + 4 * i; if (m >= 13) continue;
      floatx4 acc = bia0[i];
      acc = __builtin_amdgcn_mfma_f32_16x16x32_f16(a0[i][0], b0f[0], acc, 0, 0, 0);
      acc = __builtin_amdgcn_mfma_f32_16x16x32_f16(a0[i][1], b0f[1], acc, 0, 0, 0);
      z[i] = acc;
    }
    // x(t+1) into the other parity (slot never read this step)
    if (tid < 192) sm.act0[1 - p][xr][xf] = (_Float16)xnext;
#pragma unroll
    for (int i = 0; i < 4; ++i) {
      int m = w + 4 * i; if (m >= 13) continue;
      float ig = fsig(z[i][0]), fg = fsig(z[i][1]);
      float gg = ftanh(z[i][2]), og = fsig(z[i][3]);
      float c = fg * c0[i] + ig * gg;
      c0[i] = c;
      float h = og * ftanh(c);
      int u = 4 * m + q;
      if (u < 50) {
        _Float16 hh = (_Float16)h;
        sm.act0[1 - p][n][12 + u] = hh;   // recurrence input for t+1
        sm.act1[p][n][u] = hh;            // feeds layer 1 now
      }
    }
    // prefetch x(t+2)
    if (tid < 192) {
      size_t base = (size_t)(blk * BT + xr) * Tt;
      xnext = (t + 2 < Tt) ? x[(base + t + 2) * 12 + xf] : 0.f;
    }
    __syncthreads();

    // ================= layer 1 =================
    half8 b1f[4];
#pragma unroll
    for (int kc = 0; kc < 4; ++kc)
      b1f[kc] = *(const half8*)&sm.act1[p][n][kc * 32 + q * 8];
#pragma unroll
    for (int i = 0; i < 4; ++i) {
      int m = w + 4 * i; if (m >= 13) continue;
      floatx4 acc = bia1[i];
#pragma unroll
      for (int kc = 0; kc < 4; ++kc)
        acc = __builtin_amdgcn_mfma_f32_16x16x32_f16(a1[i][kc], b1f[kc], acc, 0, 0, 0);
      z[i] = acc;
    }
#pragma unroll
    for (int i = 0; i < 4; ++i) {
      int m = w + 4 * i; if (m >= 13) continue;
      float ig = fsig(z[i][0]), fg = fsig(z[i][1]);
      float gg = ftanh(z[i][2]), og = fsig(z[i][3]);
      float c = fg * c1[i] + ig * gg;
      c1[i] = c;
      float h = og * ftanh(c);
      int u = 4 * m + q;
      if (u < 50) {
        _Float16 hh = (_Float16)h;
        sm.act1[1 - p][n][50 + u] = hh;   // self-recurrence for t+1
        sm.act2[p][n][u] = hh;            // feeds layer 2 now
      }
    }
    __syncthreads();

    // ================= layer 2 =================
    half8 b2f[4];
#pragma unroll
    for (int kc = 0; kc < 4; ++kc)
      b2f[kc] = *(const half8*)&sm.act2[p][n][kc * 32 + q * 8];
#pragma unroll
    for (int i = 0; i < 4; ++i) {
      int m = w + 4 * i; if (m >= 13) continue;
      floatx4 acc = bia2[i];
#pragma unroll
      for (int kc = 0; kc < 4; ++kc)
        acc = __builtin_amdgcn_mfma_f32_16x16x32_f16(a2[i][kc], b2f[kc], acc, 0, 0, 0);
      z[i] = acc;
    }
#pragma unroll
    for (int i = 0; i < 4; ++i) {
      int m = w + 4 * i; if (m >= 13) continue;
      float ig = fsig(z[i][0]), fg = fsig(z[i][1]);
      float gg = ftanh(z[i][2]), og = fsig(z[i][3]);
      float c = fg * c2[i] + ig * gg;
      c2[i] = c;
      float h = og * ftanh(c);
      int u = 4 * m + q;
      if (u < 50)
        sm.act2[1 - p][n][50 + u] = (_Float16)h;  // self-recurrence / final output
    }
    // no barrier needed here: next step's layer-0 touches only act0/act1,
    // and all act2[p]-readers already passed this step's second barrier.
  }
  __syncthreads();

  // ---- epilogue: out[r] = b_lin + h2(T-1) . W_lin ----
  // T-1 = 335 (p=1) wrote act2[0][n][50+u]
  if (tid < BT) {
    float s = blin[0];
    for (int u = 0; u < 50; ++u)
      s += Wlin[u] * (float)sm.act2[0][tid][50 + u];
    out[blk * BT + tid] = s;
  }
}

extern "C" void kernel_launch(void* const* d_in, const int* in_sizes, int n_in,
                              void* d_out, int out_size, void* d_ws, size_t ws_size,
                              hipStream_t stream) {
  const float* x    = (const float*)d_in[0];
  const float* Wih0 = (const float*)d_in[1];
  const float* Whh0 = (const float*)d_in[2];
  const float* bih0 = (const float*)d_in[3];
  const float* bhh0 = (const float*)d_in[4];
  const float* Wih1 = (const float*)d_in[5];
  const float* Whh1 = (const float*)d_in[6];
  const float* bih1 = (const float*)d_in[7];
  const float* bhh1 = (const float*)d_in[8];
  const float* Wih2 = (const float*)d_in[9];
  const float* Whh2 = (const float*)d_in[10];
  const float* bih2 = (const float*)d_in[11];
  const float* bhh2 = (const float*)d_in[12];
  const float* Wlin = (const float*)d_in[13];
  const float* blin = (const float*)d_in[14];
  float* outp = (float*)d_out;

  dim3 grid(Bsz / BT);   // 256 blocks, 1 per CU
  dim3 block(NTH);       // 4 waves
  lstm_mfma_kernel<<<grid, block, 0, stream>>>(
      x, Wih0, Whh0, bih0, bhh0, Wih1, Whh1, bih1, bhh1,
      Wih2, Whh2, bih2, bhh2, Wlin, blin, outp);
}

// Round 3
// 580.640 us; speedup vs baseline: 6.3796x; 1.4440x over previous
//
#include <hip/hip_runtime.h>

// 3-layer LSTM, B=4096, T=336, F=12, H=50, fp32 in/out.
// MFMA formulation: z^T = W'(gate-permuted) @ a^T via mfma_f32_16x16x32_f16.
// Row permutation R = 4*unit + gate puts all 4 gates of a unit into one
// lane's 4 accumulators -> lane-local c/h update, c in registers for all T.
// Weights in VGPRs (loaded once). 512 threads (8 waves, 2/SIMD for latency
// hiding), 13 M-tiles striped m = w + 8i. Activation planes in LDS with
// bank-balanced strides (36/68 dwords, ==4 mod 8 -> b128 reads conflict-free)
// and pair-packed b32 h-writes via ds_swizzle xor-16 (2-way banks = free).

#define Bsz 4096
#define Tt  336
#define BT  16
#define NTH 512

typedef _Float16 half8 __attribute__((ext_vector_type(8)));
typedef float    floatx4 __attribute__((ext_vector_type(4)));

#define S0  72    // act0 row (halfs): [x(0..11) | h0(12..61) | pad] ; 36 dw
#define S12 136   // act1/2 row: [h_in(0..49) | h_self(50..99) | pad] ; 68 dw

struct __align__(16) SMem {
  _Float16 act0[2][BT][S0];    // 4608 B
  _Float16 act1[2][BT][S12];   // 8704 B
  _Float16 act2[2][BT][S12];   // 8704 B
};  // 22016 B

__device__ __forceinline__ float fsig(float x) {
  return __builtin_amdgcn_rcpf(1.f + __builtin_amdgcn_exp2f(-1.442695041f * x));
}
__device__ __forceinline__ float ftanh(float x) {
  return 1.f - 2.f * __builtin_amdgcn_rcpf(1.f + __builtin_amdgcn_exp2f(2.885390082f * x));
}

// Pack own h (RNE fp16) with partner lane's (lane xor 16) into one dword.
// Low half = even-q lane's value. All lanes must execute (swizzle).
__device__ __forceinline__ unsigned packpair(float h) {
  unsigned hx = (unsigned)__builtin_bit_cast(unsigned short, (_Float16)h);
  int sw = __builtin_amdgcn_ds_swizzle((int)hx, 0x401F);  // lane ^= 16
  return ((unsigned)sw << 16) | hx;
}

// A-fragment (8 halfs) of gate-permuted weights. Permuted row R = 4*u + g;
// source row = g*50+u. k<bound -> Wih[row][k]; bound<=k<bound+50 -> Whh.
__device__ __forceinline__ half8 wfrag(const float* __restrict__ Wih,
                                       const float* __restrict__ Whh,
                                       int lenih, int bound, int R, int k0) {
  half8 r = {};
  int u = R >> 2, g = R & 3;
  if (u < 50) {
    int row = g * 50 + u;
#pragma unroll
    for (int j = 0; j < 8; ++j) {
      int k = k0 + j;
      float v = 0.f;
      if (k < bound)           v = Wih[row * lenih + k];
      else if (k < bound + 50) v = Whh[row * 50 + (k - bound)];
      r[j] = (_Float16)v;
    }
  }
  return r;
}

__global__ __launch_bounds__(NTH, 2)
void lstm_mfma_kernel(const float* __restrict__ x,
                      const float* __restrict__ Wih0, const float* __restrict__ Whh0,
                      const float* __restrict__ bih0, const float* __restrict__ bhh0,
                      const float* __restrict__ Wih1, const float* __restrict__ Whh1,
                      const float* __restrict__ bih1, const float* __restrict__ bhh1,
                      const float* __restrict__ Wih2, const float* __restrict__ Whh2,
                      const float* __restrict__ bih2, const float* __restrict__ bhh2,
                      const float* __restrict__ Wlin, const float* __restrict__ blin,
                      float* __restrict__ out) {
  __shared__ SMem sm;
  const int tid  = threadIdx.x;
  const int blk  = blockIdx.x;
  const int lane = tid & 63;
  const int w    = tid >> 6;      // wave 0..7
  const int n    = lane & 15;     // batch col / A-row within tile
  const int q    = lane >> 4;     // quad: k-subgroup for B, D-row group

  // ---- zero LDS (h(-1)=0 and pads) ----
  {
    int* zp = (int*)&sm;
    for (int i = tid; i < (int)(sizeof(SMem) / 4); i += NTH) zp[i] = 0;
  }

  // ---- weight fragments + biases into registers (once) ----
  // wave w owns tiles m = w + 8*i (i<2, valid while m<13); tile m = units 4m..4m+3
  half8 a0f[2][2], a1f[2][4], a2f[2][4];
  floatx4 bia0[2], bia1[2], bia2[2];
#pragma unroll
  for (int i = 0; i < 2; ++i) {
    int m = w + 8 * i;
    bool val = (m < 13);
    int mm = val ? m : 0;
    int R = 16 * mm + n;
#pragma unroll
    for (int kc = 0; kc < 2; ++kc)
      a0f[i][kc] = val ? wfrag(Wih0, Whh0, 12, 12, R, kc * 32 + q * 8) : (half8){};
#pragma unroll
    for (int kc = 0; kc < 4; ++kc) {
      a1f[i][kc] = val ? wfrag(Wih1, Whh1, 50, 50, R, kc * 32 + q * 8) : (half8){};
      a2f[i][kc] = val ? wfrag(Wih2, Whh2, 50, 50, R, kc * 32 + q * 8) : (half8){};
    }
    floatx4 b0v = {0,0,0,0}, b1v = {0,0,0,0}, b2v = {0,0,0,0};
    int u = 4 * mm + q;
    if (val && u < 50) {
#pragma unroll
      for (int g = 0; g < 4; ++g) {
        b0v[g] = bih0[g * 50 + u] + bhh0[g * 50 + u];
        b1v[g] = bih1[g * 50 + u] + bhh1[g * 50 + u];
        b2v[g] = bih2[g * 50 + u] + bhh2[g * 50 + u];
      }
    }
    bia0[i] = b0v; bia1[i] = b1v; bia2[i] = b2v;
  }

  float c0[2] = {0, 0}, c1[2] = {0, 0}, c2[2] = {0, 0};

  // ---- stage x(0), prefetch x(1) ----
  const int xr = tid / 12, xf = tid - (tid / 12) * 12;  // active for tid<192
  const float* xp = x + (size_t)(blk * BT + xr) * Tt * 12 + xf;
  float xnext = 0.f;
  if (tid < 192) {
    sm.act0[0][xr][xf] = (_Float16)xp[0];
    xnext = xp[12];
  }
  __syncthreads();

  for (int t = 0; t < Tt; ++t) {
    const int p = t & 1;

    // ================= layer 0 =================
    half8 bf0[2];
#pragma unroll
    for (int kc = 0; kc < 2; ++kc)
      bf0[kc] = *(const half8*)&sm.act0[p][n][kc * 32 + q * 8];
    floatx4 z[2];
#pragma unroll
    for (int i = 0; i < 2; ++i) {
      int m = w + 8 * i; if (m >= 13) continue;
      floatx4 acc = bia0[i];
      acc = __builtin_amdgcn_mfma_f32_16x16x32_f16(a0f[i][0], bf0[0], acc, 0, 0, 0);
      acc = __builtin_amdgcn_mfma_f32_16x16x32_f16(a0f[i][1], bf0[1], acc, 0, 0, 0);
      z[i] = acc;
    }
    if (tid < 192) sm.act0[1 - p][xr][xf] = (_Float16)xnext;  // x(t+1)
#pragma unroll
    for (int i = 0; i < 2; ++i) {
      int m = w + 8 * i; if (m >= 13) continue;
      float ig = fsig(z[i][0]), fg = fsig(z[i][1]);
      float gg = ftanh(z[i][2]), og = fsig(z[i][3]);
      float c = fg * c0[i] + ig * gg;
      c0[i] = c;
      float h = og * ftanh(c);
      unsigned pk = packpair(h);           // all lanes
      int u = 4 * m + q;
      if (!(q & 1) && u < 50) {
        *(unsigned*)&sm.act0[1 - p][n][12 + u] = pk;  // recurrence for t+1
        *(unsigned*)&sm.act1[p][n][u]          = pk;  // feeds layer 1 now
      }
    }
    if (tid < 192) xnext = (t + 2 < Tt) ? xp[(t + 2) * 12] : 0.f;  // prefetch
    __syncthreads();

    // ================= layer 1 =================
    half8 bf1[4];
#pragma unroll
    for (int kc = 0; kc < 4; ++kc)
      bf1[kc] = *(const half8*)&sm.act1[p][n][kc * 32 + q * 8];
#pragma unroll
    for (int i = 0; i < 2; ++i) {
      int m = w + 8 * i; if (m >= 13) continue;
      floatx4 acc = bia1[i];
#pragma unroll
      for (int kc = 0; kc < 4; ++kc)
        acc = __builtin_amdgcn_mfma_f32_16x16x32_f16(a1f[i][kc], bf1[kc], acc, 0, 0, 0);
      z[i] = acc;
    }
#pragma unroll
    for (int i = 0; i < 2; ++i) {
      int m = w + 8 * i; if (m >= 13) continue;
      float ig = fsig(z[i][0]), fg = fsig(z[i][1]);
      float gg = ftanh(z[i][2]), og = fsig(z[i][3]);
      float c = fg * c1[i] + ig * gg;
      c1[i] = c;
      float h = og * ftanh(c);
      unsigned pk = packpair(h);
      int u = 4 * m + q;
      if (!(q & 1) && u < 50) {
        *(unsigned*)&sm.act1[1 - p][n][50 + u] = pk;  // self-recurrence t+1
        *(unsigned*)&sm.act2[p][n][u]          = pk;  // feeds layer 2 now
      }
    }
    __syncthreads();

    // ================= layer 2 =================
    half8 bf2[4];
#pragma unroll
    for (int kc = 0; kc < 4; ++kc)
      bf2[kc] = *(const half8*)&sm.act2[p][n][kc * 32 + q * 8];
#pragma unroll
    for (int i = 0; i < 2; ++i) {
      int m = w + 8 * i; if (m >= 13) continue;
      floatx4 acc = bia2[i];
#pragma unroll
      for (int kc = 0; kc < 4; ++kc)
        acc = __builtin_amdgcn_mfma_f32_16x16x32_f16(a2f[i][kc], bf2[kc], acc, 0, 0, 0);
      z[i] = acc;
    }
#pragma unroll
    for (int i = 0; i < 2; ++i) {
      int m = w + 8 * i; if (m >= 13) continue;
      float ig = fsig(z[i][0]), fg = fsig(z[i][1]);
      float gg = ftanh(z[i][2]), og = fsig(z[i][3]);
      float c = fg * c2[i] + ig * gg;
      c2[i] = c;
      float h = og * ftanh(c);
      unsigned pk = packpair(h);
      int u = 4 * m + q;
      if (!(q & 1) && u < 50)
        *(unsigned*)&sm.act2[1 - p][n][50 + u] = pk;  // self-rec / final out
    }
    // no barrier here: next step's layer-0 only touches act0/act1, and all
    // act2 readers of this parity already passed this step's 2nd barrier.
  }
  __syncthreads();

  // ---- epilogue: out[r] = b_lin + h2(T-1) . W_lin ----
  // t=335 (p=1) wrote act2[0][n][50+u]
  if (tid < BT) {
    float s = blin[0];
    for (int u = 0; u < 50; ++u)
      s += Wlin[u] * (float)sm.act2[0][tid][50 + u];
    out[blk * BT + tid] = s;
  }
}

extern "C" void kernel_launch(void* const* d_in, const int* in_sizes, int n_in,
                              void* d_out, int out_size, void* d_ws, size_t ws_size,
                              hipStream_t stream) {
  const float* x    = (const float*)d_in[0];
  const float* Wih0 = (const float*)d_in[1];
  const float* Whh0 = (const float*)d_in[2];
  const float* bih0 = (const float*)d_in[3];
  const float* bhh0 = (const float*)d_in[4];
  const float* Wih1 = (const float*)d_in[5];
  const float* Whh1 = (const float*)d_in[6];
  const float* bih1 = (const float*)d_in[7];
  const float* bhh1 = (const float*)d_in[8];
  const float* Wih2 = (const float*)d_in[9];
  const float* Whh2 = (const float*)d_in[10];
  const float* bih2 = (const float*)d_in[11];
  const float* bhh2 = (const float*)d_in[12];
  const float* Wlin = (const float*)d_in[13];
  const float* blin = (const float*)d_in[14];
  float* outp = (float*)d_out;

  dim3 grid(Bsz / BT);   // 256 blocks, 1 per CU
  dim3 block(NTH);       // 8 waves -> 2 per SIMD
  lstm_mfma_kernel<<<grid, block, 0, stream>>>(
      x, Wih0, Whh0, bih0, bhh0, Wih1, Whh1, bih1, bhh1,
      Wih2, Whh2, bih2, bhh2, Wlin, blin, outp);
}

// Round 4
// 476.959 us; speedup vs baseline: 7.7664x; 1.2174x over previous
//
#include <hip/hip_runtime.h>

// 3-layer LSTM, B=4096, T=336, F=12, H=50, fp32 in/out.
// MFMA: z^T = W'(gate-permuted, gate-prescaled) @ a^T via mfma_f32_16x16x32_f16.
// R = 4*unit + gate -> each lane's 4 accumulators = 4 gates of one unit ->
// lane-local c/h update; c in registers for all 336 steps; weights in VGPRs.
// 1024 threads (16 waves = 4/SIMD): waves 0..12 own one 16-row M-tile each,
// waves 13..15 stage x. LDS act planes use XOR-chunk swizzle (chunk c of row
// n at c^n) so b128 B-reads are bank-balanced and b16 h-writes are ~free.

#define Bsz 4096
#define Tt  336
#define BT  16
#define NTH 1024
#define NTILE 13

typedef _Float16 half8 __attribute__((ext_vector_type(8)));
typedef float    floatx4 __attribute__((ext_vector_type(4)));

// act0 row: 64 halfs = 8 chunks (16B). [x 0..11 | h0 12..61 | pad 62..63]
// act1/2 row: 128 halfs = 16 chunks. [h_in 0..49 | h_self 50..99 | pad]
struct __align__(16) SMem {
  _Float16 act0[2][BT * 64];
  _Float16 act1[2][BT * 128];
  _Float16 act2[2][BT * 128];
};  // 20480 B

__device__ __forceinline__ int offA0(int n, int L) {
  return n * 64 + ((((L >> 3) ^ n) & 7) << 3) + (L & 7);
}
__device__ __forceinline__ int offA12(int n, int L) {
  return n * 128 + ((((L >> 3) ^ n) & 15) << 3) + (L & 7);
}

// z is gate-prescaled: gates i,f,o hold -log2(e)*z ; gate g holds 2*log2(e)*z.
__device__ __forceinline__ float lstm_cell(floatx4 z, float& c) {
  float ei = __builtin_amdgcn_exp2f(z[0]);
  float ef = __builtin_amdgcn_exp2f(z[1]);
  float eg = __builtin_amdgcn_exp2f(z[2]);
  float eo = __builtin_amdgcn_exp2f(z[3]);
  float ig = __builtin_amdgcn_rcpf(1.f + ei);   // sigmoid
  float fg = __builtin_amdgcn_rcpf(1.f + ef);
  float rg = __builtin_amdgcn_rcpf(1.f + eg);
  float og = __builtin_amdgcn_rcpf(1.f + eo);
  float gg = 1.f - 2.f * rg;                    // tanh
  c = fg * c + ig * gg;
  float ec = __builtin_amdgcn_exp2f(2.885390082f * c);
  float rc = __builtin_amdgcn_rcpf(1.f + ec);
  return og * (1.f - 2.f * rc);                 // o * tanh(c)
}

// A-fragment (8 halfs) of gate-permuted, gate-prescaled weights.
// R = 4*u + g; source row g*50+u. k<bound -> Wih; bound<=k<bound+50 -> Whh.
__device__ __forceinline__ half8 wfrag(const float* __restrict__ Wih,
                                       const float* __restrict__ Whh,
                                       int lenih, int bound, int R, int k0) {
  half8 r = {};
  int u = R >> 2, g = R & 3;
  float sc = (g == 2) ? 2.885390082f : -1.442695041f;
  if (u < 50) {
    int row = g * 50 + u;
#pragma unroll
    for (int j = 0; j < 8; ++j) {
      int k = k0 + j;
      float v = 0.f;
      if (k < bound)           v = Wih[row * lenih + k];
      else if (k < bound + 50) v = Whh[row * 50 + (k - bound)];
      r[j] = (_Float16)(sc * v);
    }
  }
  return r;
}

#define MFMA(a, b, acc) __builtin_amdgcn_mfma_f32_16x16x32_f16((a), (b), (acc), 0, 0, 0)

__global__ __launch_bounds__(NTH, 4)
void lstm_mfma_kernel(const float* __restrict__ x,
                      const float* __restrict__ Wih0, const float* __restrict__ Whh0,
                      const float* __restrict__ bih0, const float* __restrict__ bhh0,
                      const float* __restrict__ Wih1, const float* __restrict__ Whh1,
                      const float* __restrict__ bih1, const float* __restrict__ bhh1,
                      const float* __restrict__ Wih2, const float* __restrict__ Whh2,
                      const float* __restrict__ bih2, const float* __restrict__ bhh2,
                      const float* __restrict__ Wlin, const float* __restrict__ blin,
                      float* __restrict__ out) {
  __shared__ SMem sm;
  const int tid  = threadIdx.x;
  const int blk  = blockIdx.x;
  const int lane = tid & 63;
  const int w    = tid >> 6;       // wave 0..15
  const int n    = lane & 15;      // batch col / A-row in tile
  const int q    = lane >> 4;      // quad
  const bool hasTile = (w < NTILE);
  const int u    = 4 * w + q;      // unit for D-frag lanes (tile w)
  const bool uok = hasTile && (u < 50);
  const int uc   = (u < 50) ? u : 0;   // clamped for safe offset math

  // ---- zero LDS (h(-1)=0, pads=0) ----
  {
    int* zp = (int*)&sm;
    for (int i = tid; i < (int)(sizeof(SMem) / 4); i += NTH) zp[i] = 0;
  }

  // ---- weight fragments + biases (registers, once) ----
  half8 a0f[2] = {}, a1f[4] = {}, a2f[4] = {};
  floatx4 bia0 = {0,0,0,0}, bia1 = {0,0,0,0}, bia2 = {0,0,0,0};
  if (hasTile) {
    int R = 16 * w + n;
#pragma unroll
    for (int kc = 0; kc < 2; ++kc)
      a0f[kc] = wfrag(Wih0, Whh0, 12, 12, R, kc * 32 + q * 8);
#pragma unroll
    for (int kc = 0; kc < 4; ++kc) {
      a1f[kc] = wfrag(Wih1, Whh1, 50, 50, R, kc * 32 + q * 8);
      a2f[kc] = wfrag(Wih2, Whh2, 50, 50, R, kc * 32 + q * 8);
    }
    if (u < 50) {
#pragma unroll
      for (int g = 0; g < 4; ++g) {
        float sc = (g == 2) ? 2.885390082f : -1.442695041f;
        bia0[g] = sc * (bih0[g * 50 + u] + bhh0[g * 50 + u]);
        bia1[g] = sc * (bih1[g * 50 + u] + bhh1[g * 50 + u]);
        bia2[g] = sc * (bih2[g * 50 + u] + bhh2[g * 50 + u]);
      }
    }
  }

  // ---- lane-constant LDS offsets (halfs) ----
  const int ro0[2] = { offA0(n, q * 8), offA0(n, 32 + q * 8) };
  const int ro1[4] = { offA12(n, q * 8),      offA12(n, 32 + q * 8),
                       offA12(n, 64 + q * 8), offA12(n, 96 + q * 8) };
  const int wr0 = offA0 (n, 12 + uc);   // act0 recurrence slot
  const int wrA = offA12(n, uc);        // h -> next layer input region
  const int wrB = offA12(n, 50 + uc);   // h -> self-recurrence region

  // ---- stager setup (waves 13..15 = 192 threads = 16 rows x 12 feats) ----
  const int tid0 = tid - NTILE * 64;
  const int sr = (tid0 >= 0) ? tid0 / 12 : 0;
  const int sf = (tid0 >= 0) ? tid0 - sr * 12 : 0;
  const int sxo = offA0(sr, sf);
  const float* xp = x + ((size_t)(blk * BT + sr) * Tt) * 12 + sf;
  float xnext = 0.f;

  __syncthreads();   // zero-fill visible
  if (!hasTile) {
    sm.act0[0][sxo] = (_Float16)xp[0];   // x(0)
    xnext = xp[12];                      // x(1)
  }
  __syncthreads();

  float c0 = 0.f, c1 = 0.f, c2 = 0.f;

#define STEP(p, t)                                                         \
  {                                                                        \
    if (hasTile) {                                                         \
      half8 b0 = *(const half8*)&sm.act0[p][ro0[0]];                       \
      half8 b1 = *(const half8*)&sm.act0[p][ro0[1]];                       \
      floatx4 z = bia0;                                                    \
      z = MFMA(a0f[0], b0, z);                                             \
      z = MFMA(a0f[1], b1, z);                                             \
      float h = lstm_cell(z, c0);                                          \
      _Float16 hh = (_Float16)h;                                           \
      if (uok) { sm.act0[1 - (p)][wr0] = hh; sm.act1[p][wrA] = hh; }       \
    } else {                                                               \
      if ((t) + 1 < Tt) sm.act0[1 - (p)][sxo] = (_Float16)xnext;           \
      xnext = ((t) + 2 < Tt) ? xp[((t) + 2) * 12] : 0.f;                   \
    }                                                                      \
    __syncthreads();                                                       \
    if (hasTile) {                                                         \
      half8 b0 = *(const half8*)&sm.act1[p][ro1[0]];                       \
      half8 b1 = *(const half8*)&sm.act1[p][ro1[1]];                       \
      half8 b2 = *(const half8*)&sm.act1[p][ro1[2]];                       \
      half8 b3 = *(const half8*)&sm.act1[p][ro1[3]];                       \
      floatx4 z = bia1;                                                    \
      z = MFMA(a1f[0], b0, z);                                             \
      z = MFMA(a1f[1], b1, z);                                             \
      z = MFMA(a1f[2], b2, z);                                             \
      z = MFMA(a1f[3], b3, z);                                             \
      float h = lstm_cell(z, c1);                                          \
      _Float16 hh = (_Float16)h;                                           \
      if (uok) { sm.act1[1 - (p)][wrB] = hh; sm.act2[p][wrA] = hh; }       \
    }                                                                      \
    __syncthreads();                                                       \
    if (hasTile) {                                                         \
      half8 b0 = *(const half8*)&sm.act2[p][ro1[0]];                       \
      half8 b1 = *(const half8*)&sm.act2[p][ro1[1]];                       \
      half8 b2 = *(const half8*)&sm.act2[p][ro1[2]];                       \
      half8 b3 = *(const half8*)&sm.act2[p][ro1[3]];                       \
      floatx4 z = bia2;                                                    \
      z = MFMA(a2f[0], b0, z);                                             \
      z = MFMA(a2f[1], b1, z);                                             \
      z = MFMA(a2f[2], b2, z);                                             \
      z = MFMA(a2f[3], b3, z);                                             \
      float h = lstm_cell(z, c2);                                          \
      if (uok) sm.act2[1 - (p)][wrB] = (_Float16)h;                        \
    }                                                                      \
    /* no 3rd barrier: next-step readers of planes written here cross   */ \
    /* both barriers of the next step before reading; act0/act1 reads   */ \
    /* at next step touch only data written before this step's barriers */ \
  }

  for (int t = 0; t < Tt; t += 2) {
    STEP(0, t)
    STEP(1, t + 1)
  }
#undef STEP

  __syncthreads();

  // ---- epilogue: out[r] = b_lin + h2(T-1) . W_lin ----
  // t=335 (p=1) wrote act2[0][.][50+u]
  if (tid < BT) {
    float s = blin[0];
    for (int uu = 0; uu < 50; ++uu)
      s += Wlin[uu] * (float)sm.act2[0][offA12(tid, 50 + uu)];
    out[blk * BT + tid] = s;
  }
}

extern "C" void kernel_launch(void* const* d_in, const int* in_sizes, int n_in,
                              void* d_out, int out_size, void* d_ws, size_t ws_size,
                              hipStream_t stream) {
  const float* x    = (const float*)d_in[0];
  const float* Wih0 = (const float*)d_in[1];
  const float* Whh0 = (const float*)d_in[2];
  const float* bih0 = (const float*)d_in[3];
  const float* bhh0 = (const float*)d_in[4];
  const float* Wih1 = (const float*)d_in[5];
  const float* Whh1 = (const float*)d_in[6];
  const float* bih1 = (const float*)d_in[7];
  const float* bhh1 = (const float*)d_in[8];
  const float* Wih2 = (const float*)d_in[9];
  const float* Whh2 = (const float*)d_in[10];
  const float* bih2 = (const float*)d_in[11];
  const float* bhh2 = (const float*)d_in[12];
  const float* Wlin = (const float*)d_in[13];
  const float* blin = (const float*)d_in[14];
  float* outp = (float*)d_out;

  dim3 grid(Bsz / BT);   // 256 blocks, 1 per CU
  dim3 block(NTH);       // 16 waves -> 4 per SIMD
  lstm_mfma_kernel<<<grid, block, 0, stream>>>(
      x, Wih0, Whh0, bih0, bhh0, Wih1, Whh1, bih1, bhh1,
      Wih2, Whh2, bih2, bhh2, Wlin, blin, outp);
}

// Round 5
// 459.542 us; speedup vs baseline: 8.0608x; 1.0379x over previous
//
#include <hip/hip_runtime.h>

// 3-layer LSTM, B=4096, T=336, F=12, H=50, fp32 in/out.
// MFMA: z^T = W'(gate-permuted, gate-prescaled) @ a^T via mfma_f32_16x16x32_f16.
// R = 4*unit + gate -> each lane's 4 accumulators = 4 gates of one unit ->
// lane-local c/h update; c in registers for all 336 steps; weights in VGPRs.
// LAYER-PIPELINED: at tick tau, L0 computes step tau, L1 step tau-1, L2 step
// tau-2 -- mutually independent, all inputs produced last tick -> 3x ILP and
// ONE barrier per tick (was 3 serial phases + 2 barriers per step).
// 1024 threads (16 waves = 4/SIMD): waves 0..12 own one 16-row M-tile for all
// 3 layers; waves 13..15 stage x. LDS act planes XOR-chunk swizzled.

#define Bsz 4096
#define Tt  336
#define BT  16
#define NTH 1024
#define NTILE 13

typedef _Float16 half8 __attribute__((ext_vector_type(8)));
typedef float    floatx4 __attribute__((ext_vector_type(4)));

// act0 row: 64 halfs = 8 chunks (16B). [x 0..11 | h0 12..61 | pad]
// act1/2 row: 128 halfs = 16 chunks. [h_in 0..49 | h_self 50..99 | pad]
struct __align__(16) SMem {
  _Float16 act0[2][BT * 64];
  _Float16 act1[2][BT * 128];
  _Float16 act2[2][BT * 128];
};  // 20480 B

__device__ __forceinline__ int offA0(int n, int L) {
  return n * 64 + ((((L >> 3) ^ n) & 7) << 3) + (L & 7);
}
__device__ __forceinline__ int offA12(int n, int L) {
  return n * 128 + ((((L >> 3) ^ n) & 15) << 3) + (L & 7);
}

// z gate-prescaled: gates i,f,o hold -log2(e)*z ; gate g holds 2*log2(e)*z.
__device__ __forceinline__ float lstm_cell(floatx4 z, float& c) {
  float ei = __builtin_amdgcn_exp2f(z[0]);
  float ef = __builtin_amdgcn_exp2f(z[1]);
  float eg = __builtin_amdgcn_exp2f(z[2]);
  float eo = __builtin_amdgcn_exp2f(z[3]);
  float ig = __builtin_amdgcn_rcpf(1.f + ei);   // sigmoid(i)
  float fg = __builtin_amdgcn_rcpf(1.f + ef);   // sigmoid(f)
  float rg = __builtin_amdgcn_rcpf(1.f + eg);
  float og = __builtin_amdgcn_rcpf(1.f + eo);   // sigmoid(o)
  float gg = 1.f - 2.f * rg;                    // tanh(g)
  c = fg * c + ig * gg;
  float ec = __builtin_amdgcn_exp2f(2.885390082f * c);
  float rc = __builtin_amdgcn_rcpf(1.f + ec);
  return og * (1.f - 2.f * rc);                 // o * tanh(c)
}

// A-fragment (8 halfs) of gate-permuted, gate-prescaled weights.
// R = 4*u + g; source row g*50+u. k<bound -> Wih; bound<=k<bound+50 -> Whh.
__device__ __forceinline__ half8 wfrag(const float* __restrict__ Wih,
                                       const float* __restrict__ Whh,
                                       int lenih, int bound, int R, int k0) {
  half8 r = {};
  int u = R >> 2, g = R & 3;
  float sc = (g == 2) ? 2.885390082f : -1.442695041f;
  if (u < 50) {
    int row = g * 50 + u;
#pragma unroll
    for (int j = 0; j < 8; ++j) {
      int k = k0 + j;
      float v = 0.f;
      if (k < bound)           v = Wih[row * lenih + k];
      else if (k < bound + 50) v = Whh[row * 50 + (k - bound)];
      r[j] = (_Float16)(sc * v);
    }
  }
  return r;
}

#define MFMA(a, b, acc) __builtin_amdgcn_mfma_f32_16x16x32_f16((a), (b), (acc), 0, 0, 0)

__global__ __launch_bounds__(NTH, 4)
void lstm_mfma_kernel(const float* __restrict__ x,
                      const float* __restrict__ Wih0, const float* __restrict__ Whh0,
                      const float* __restrict__ bih0, const float* __restrict__ bhh0,
                      const float* __restrict__ Wih1, const float* __restrict__ Whh1,
                      const float* __restrict__ bih1, const float* __restrict__ bhh1,
                      const float* __restrict__ Wih2, const float* __restrict__ Whh2,
                      const float* __restrict__ bih2, const float* __restrict__ bhh2,
                      const float* __restrict__ Wlin, const float* __restrict__ blin,
                      float* __restrict__ out) {
  __shared__ SMem sm;
  const int tid  = threadIdx.x;
  const int blk  = blockIdx.x;
  const int lane = tid & 63;
  const int w    = tid >> 6;       // wave 0..15
  const int n    = lane & 15;      // batch col / A-row in tile
  const int q    = lane >> 4;      // quad
  const bool hasTile = (w < NTILE);
  const int u    = 4 * w + q;      // unit owned by this lane (tile w)
  const bool uok = hasTile && (u < 50);
  const int uc   = (u < 50) ? u : 0;

  // ---- zero LDS (h(-1)=0 for all layers/parities, pads=0) ----
  {
    int* zp = (int*)&sm;
    for (int i = tid; i < (int)(sizeof(SMem) / 4); i += NTH) zp[i] = 0;
  }

  // ---- weight fragments + biases (registers, once) ----
  half8 a0f[2] = {}, a1f[4] = {}, a2f[4] = {};
  floatx4 bia0 = {0,0,0,0}, bia1 = {0,0,0,0}, bia2 = {0,0,0,0};
  if (hasTile) {
    int R = 16 * w + n;
#pragma unroll
    for (int kc = 0; kc < 2; ++kc)
      a0f[kc] = wfrag(Wih0, Whh0, 12, 12, R, kc * 32 + q * 8);
#pragma unroll
    for (int kc = 0; kc < 4; ++kc) {
      a1f[kc] = wfrag(Wih1, Whh1, 50, 50, R, kc * 32 + q * 8);
      a2f[kc] = wfrag(Wih2, Whh2, 50, 50, R, kc * 32 + q * 8);
    }
    if (u < 50) {
#pragma unroll
      for (int g = 0; g < 4; ++g) {
        float sc = (g == 2) ? 2.885390082f : -1.442695041f;
        bia0[g] = sc * (bih0[g * 50 + u] + bhh0[g * 50 + u]);
        bia1[g] = sc * (bih1[g * 50 + u] + bhh1[g * 50 + u]);
        bia2[g] = sc * (bih2[g * 50 + u] + bhh2[g * 50 + u]);
      }
    }
  }

  // ---- lane-constant LDS offsets (halfs) ----
  const int ro0[2] = { offA0(n, q * 8), offA0(n, 32 + q * 8) };
  const int ro1[4] = { offA12(n, q * 8),      offA12(n, 32 + q * 8),
                       offA12(n, 64 + q * 8), offA12(n, 96 + q * 8) };
  const int wr0 = offA0 (n, 12 + uc);   // act0 recurrence slot (h0)
  const int wrA = offA12(n, uc);        // h -> next layer's input region
  const int wrB = offA12(n, 50 + uc);   // h -> self-recurrence region

  // ---- stager setup (waves 13..15 = 192 threads = 16 rows x 12 feats) ----
  const int tid0 = tid - NTILE * 64;
  const int sr = (tid0 >= 0) ? tid0 / 12 : 0;
  const int sf = (tid0 >= 0) ? tid0 - sr * 12 : 0;
  const int sxo = offA0(sr, sf);
  const float* xp = x + ((size_t)(blk * BT + sr) * Tt) * 12 + sf;
  float xnext = 0.f;

  __syncthreads();   // zero-fill visible
  if (!hasTile) {
    sm.act0[0][sxo] = (_Float16)xp[0];   // x(0) into parity-0 buffer
    xnext = xp[12];                      // x(1)
  }
  __syncthreads();

  float c0 = 0.f, c1 = 0.f, c2 = 0.f;

  // Tick tau (parity p = tau&1): read buffers [p], write buffers [1-p].
  // L0 computes step tau, L1 step tau-1, L2 step tau-2 (DO flags gate
  // fill/drain). Stager writes x(tau+1) into act0[1-p]. One barrier.
#define TICK(p, DO0, DO1, DO2, t0)                                         \
  {                                                                        \
    if (hasTile) {                                                         \
      half8 b00{}, b01{}, b10{}, b11{}, b12{}, b13{};                      \
      half8 b20{}, b21{}, b22{}, b23{};                                    \
      if (DO0) {                                                           \
        b00 = *(const half8*)&sm.act0[p][ro0[0]];                          \
        b01 = *(const half8*)&sm.act0[p][ro0[1]];                          \
      }                                                                    \
      if (DO1) {                                                           \
        b10 = *(const half8*)&sm.act1[p][ro1[0]];                          \
        b11 = *(const half8*)&sm.act1[p][ro1[1]];                          \
        b12 = *(const half8*)&sm.act1[p][ro1[2]];                          \
        b13 = *(const half8*)&sm.act1[p][ro1[3]];                          \
      }                                                                    \
      if (DO2) {                                                           \
        b20 = *(const half8*)&sm.act2[p][ro1[0]];                          \
        b21 = *(const half8*)&sm.act2[p][ro1[1]];                          \
        b22 = *(const half8*)&sm.act2[p][ro1[2]];                          \
        b23 = *(const half8*)&sm.act2[p][ro1[3]];                          \
      }                                                                    \
      if (DO0) {                                                           \
        floatx4 z = bia0;                                                  \
        z = MFMA(a0f[0], b00, z);                                          \
        z = MFMA(a0f[1], b01, z);                                          \
        float h = lstm_cell(z, c0);                                        \
        _Float16 hh = (_Float16)h;                                         \
        if (uok) { sm.act0[1 - (p)][wr0] = hh;                             \
                   sm.act1[1 - (p)][wrA] = hh; }                           \
      }                                                                    \
      if (DO1) {                                                           \
        floatx4 z = bia1;                                                  \
        z = MFMA(a1f[0], b10, z);                                          \
        z = MFMA(a1f[1], b11, z);                                          \
        z = MFMA(a1f[2], b12, z);                                          \
        z = MFMA(a1f[3], b13, z);                                          \
        float h = lstm_cell(z, c1);                                        \
        _Float16 hh = (_Float16)h;                                         \
        if (uok) { sm.act1[1 - (p)][wrB] = hh;                             \
                   sm.act2[1 - (p)][wrA] = hh; }                           \
      }                                                                    \
      if (DO2) {                                                           \
        floatx4 z = bia2;                                                  \
        z = MFMA(a2f[0], b20, z);                                          \
        z = MFMA(a2f[1], b21, z);                                          \
        z = MFMA(a2f[2], b22, z);                                          \
        z = MFMA(a2f[3], b23, z);                                          \
        float h = lstm_cell(z, c2);                                        \
        if (uok) sm.act2[1 - (p)][wrB] = (_Float16)h;                      \
      }                                                                    \
    } else {                                                               \
      if ((t0) + 1 < Tt) sm.act0[1 - (p)][sxo] = (_Float16)xnext;          \
      xnext = ((t0) + 2 < Tt) ? xp[((t0) + 2) * 12] : 0.f;                 \
    }                                                                      \
    __syncthreads();                                                       \
  }

  // fill
  TICK(0, 1, 0, 0, 0)
  TICK(1, 1, 1, 0, 1)
  // steady: ticks 2..335 (334 ticks, unroll by 2 for literal parity)
  for (int t = 2; t < Tt; t += 2) {
    TICK(0, 1, 1, 1, t)
    TICK(1, 1, 1, 1, t + 1)
  }
  // drain: tick 336 (L1 step 335, L2 step 334), tick 337 (L2 step 335)
  TICK(0, 0, 1, 1, 336)
  TICK(1, 0, 0, 1, 337)
#undef TICK

  // ---- epilogue: out[r] = b_lin + h2(335) . W_lin ----
  // L2 step 335 ran at tick 337 (p=1) -> wrote act2[0][wrB]
  if (tid < BT) {
    float s = blin[0];
    for (int uu = 0; uu < 50; ++uu)
      s += Wlin[uu] * (float)sm.act2[0][offA12(tid, 50 + uu)];
    out[blk * BT + tid] = s;
  }
}

extern "C" void kernel_launch(void* const* d_in, const int* in_sizes, int n_in,
                              void* d_out, int out_size, void* d_ws, size_t ws_size,
                              hipStream_t stream) {
  const float* x    = (const float*)d_in[0];
  const float* Wih0 = (const float*)d_in[1];
  const float* Whh0 = (const float*)d_in[2];
  const float* bih0 = (const float*)d_in[3];
  const float* bhh0 = (const float*)d_in[4];
  const float* Wih1 = (const float*)d_in[5];
  const float* Whh1 = (const float*)d_in[6];
  const float* bih1 = (const float*)d_in[7];
  const float* bhh1 = (const float*)d_in[8];
  const float* Wih2 = (const float*)d_in[9];
  const float* Whh2 = (const float*)d_in[10];
  const float* bih2 = (const float*)d_in[11];
  const float* bhh2 = (const float*)d_in[12];
  const float* Wlin = (const float*)d_in[13];
  const float* blin = (const float*)d_in[14];
  float* outp = (float*)d_out;

  dim3 grid(Bsz / BT);   // 256 blocks, 1 per CU
  dim3 block(NTH);       // 16 waves -> 4 per SIMD
  lstm_mfma_kernel<<<grid, block, 0, stream>>>(
      x, Wih0, Whh0, bih0, bhh0, Wih1, Whh1, bih1, bhh1,
      Wih2, Whh2, bih2, bhh2, Wlin, blin, outp);
}

// Round 6
// 405.372 us; speedup vs baseline: 9.1379x; 1.1336x over previous
//
#include <hip/hip_runtime.h>

// 3-layer LSTM, B=4096, T=336, F=12, H=50, fp32 in/out.
// MFMA: z^T = W'(gate-permuted, gate-prescaled) @ a^T via mfma_f32_16x16x32_f16.
// R = 4*unit + gate -> each lane's 4 accumulators = 4 gates of one unit ->
// lane-local c/h update; c in registers; weights in VGPRs (loaded once).
// LAYER-SPECIALIZED WAVES: 39 cells = 13 tiles x 3 layers, each wave owns 2-3
// cells of ONE layer -> reads ONE activation plane (2 or 4 b128) per tick.
// Cuts LDS B-frag traffic 130KB -> 54KB per tick (round-5 bottleneck: all 13
// waves read identical frags). Layer pipelining in time: at tick tau, L0
// computes step tau, L1 step tau-1, L2 step tau-2; one barrier per tick.
// 1024 threads = 16 waves (4/SIMD); cells placed 9-10 per SIMD.

#define Bsz 4096
#define Tt  336
#define BT  16
#define NTH 1024

typedef _Float16 half8 __attribute__((ext_vector_type(8)));
typedef float    floatx4 __attribute__((ext_vector_type(4)));

// act0 row: 64 halfs = 8 chunks (16B). [x 0..11 | h0 12..61 | pad]
// act1/2 row: 128 halfs = 16 chunks. [h_in 0..49 | h_self 50..99 | pad]
// XOR-chunk swizzle: chunk c of row n stored at c ^ (n & (nchunks-1)).
struct __align__(16) SMem {
  _Float16 act0[2][BT * 64];
  _Float16 act1[2][BT * 128];
  _Float16 act2[2][BT * 128];
};  // 20480 B

__device__ __forceinline__ int offA0(int n, int L) {
  return n * 64 + ((((L >> 3) ^ n) & 7) << 3) + (L & 7);
}
__device__ __forceinline__ int offA12(int n, int L) {
  return n * 128 + ((((L >> 3) ^ n) & 15) << 3) + (L & 7);
}

// z gate-prescaled: gates i,f,o hold -log2(e)*z ; gate g holds 2*log2(e)*z.
__device__ __forceinline__ float lstm_cell(floatx4 z, float& c) {
  float ei = __builtin_amdgcn_exp2f(z[0]);
  float ef = __builtin_amdgcn_exp2f(z[1]);
  float eg = __builtin_amdgcn_exp2f(z[2]);
  float eo = __builtin_amdgcn_exp2f(z[3]);
  float ig = __builtin_amdgcn_rcpf(1.f + ei);   // sigmoid(i)
  float fg = __builtin_amdgcn_rcpf(1.f + ef);   // sigmoid(f)
  float rg = __builtin_amdgcn_rcpf(1.f + eg);
  float og = __builtin_amdgcn_rcpf(1.f + eo);   // sigmoid(o)
  float gg = 1.f - 2.f * rg;                    // tanh(g)
  c = fg * c + ig * gg;
  float ec = __builtin_amdgcn_exp2f(2.885390082f * c);
  float rc = __builtin_amdgcn_rcpf(1.f + ec);
  return og * (1.f - 2.f * rc);                 // o * tanh(c)
}

// A-fragment (8 halfs) of gate-permuted, gate-prescaled weights.
// R = 4*u + g; source row g*50+u. k<bound -> Wih; bound<=k<bound+50 -> Whh.
__device__ __forceinline__ half8 wfrag(const float* __restrict__ Wih,
                                       const float* __restrict__ Whh,
                                       int lenih, int bound, int R, int k0) {
  half8 r = {};
  int u = R >> 2, g = R & 3;
  float sc = (g == 2) ? 2.885390082f : -1.442695041f;
  if (u < 50) {
    int row = g * 50 + u;
#pragma unroll
    for (int j = 0; j < 8; ++j) {
      int k = k0 + j;
      float v = 0.f;
      if (k < bound)           v = Wih[row * lenih + k];
      else if (k < bound + 50) v = Whh[row * 50 + (k - bound)];
      r[j] = (_Float16)(sc * v);
    }
  }
  return r;
}

#define MFMA(a, b, acc) __builtin_amdgcn_mfma_f32_16x16x32_f16((a), (b), (acc), 0, 0, 0)

__global__ __launch_bounds__(NTH, 4)
void lstm_mfma_kernel(const float* __restrict__ x,
                      const float* __restrict__ Wih0, const float* __restrict__ Whh0,
                      const float* __restrict__ bih0, const float* __restrict__ bhh0,
                      const float* __restrict__ Wih1, const float* __restrict__ Whh1,
                      const float* __restrict__ bih1, const float* __restrict__ bhh1,
                      const float* __restrict__ Wih2, const float* __restrict__ Whh2,
                      const float* __restrict__ bih2, const float* __restrict__ bhh2,
                      const float* __restrict__ Wlin, const float* __restrict__ blin,
                      float* __restrict__ out) {
  __shared__ SMem sm;
  const int tid  = threadIdx.x;
  const int blk  = blockIdx.x;
  const int lane = tid & 63;
  const int w    = tid >> 6;       // wave 0..15
  const int n    = lane & 15;      // batch col / A-row in tile
  const int q    = lane >> 4;      // quad

  // ---- zero LDS (h(-1)=0 for all layers/parities, pads=0) ----
  {
    int* zp = (int*)&sm;
    for (int i = tid; i < (int)(sizeof(SMem) / 4); i += NTH) zp[i] = 0;
  }

  // ---- wave -> (layer, cells) table; SIMD k hosts waves {k,k+4,k+8,k+12},
  //      placed so each SIMD gets 9-10 cells ----
  int Lw, nc, mm3[3] = {0, 0, 0};
  switch (w) {
    case 0:  Lw = 0; nc = 3; mm3[0] = 0;  mm3[1] = 1;  mm3[2] = 2;  break;
    case 1:  Lw = 0; nc = 2; mm3[0] = 3;  mm3[1] = 4;               break;
    case 2:  Lw = 0; nc = 3; mm3[0] = 5;  mm3[1] = 6;  mm3[2] = 7;  break;
    case 3:  Lw = 0; nc = 2; mm3[0] = 8;  mm3[1] = 9;               break;
    case 4:  Lw = 1; nc = 2; mm3[0] = 0;  mm3[1] = 1;               break;
    case 5:  Lw = 1; nc = 3; mm3[0] = 2;  mm3[1] = 3;  mm3[2] = 4;  break;
    case 6:  Lw = 1; nc = 2; mm3[0] = 5;  mm3[1] = 6;               break;
    case 7:  Lw = 1; nc = 3; mm3[0] = 7;  mm3[1] = 8;  mm3[2] = 9;  break;
    case 8:  Lw = 2; nc = 3; mm3[0] = 0;  mm3[1] = 1;  mm3[2] = 2;  break;
    case 9:  Lw = 2; nc = 2; mm3[0] = 3;  mm3[1] = 4;               break;
    case 10: Lw = 2; nc = 2; mm3[0] = 5;  mm3[1] = 6;               break;
    case 11: Lw = 2; nc = 2; mm3[0] = 7;  mm3[1] = 8;               break;
    case 12: Lw = 2; nc = 2; mm3[0] = 9;  mm3[1] = 10;              break;
    case 13: Lw = 0; nc = 3; mm3[0] = 10; mm3[1] = 11; mm3[2] = 12; break;
    case 14: Lw = 1; nc = 3; mm3[0] = 10; mm3[1] = 11; mm3[2] = 12; break;
    default: Lw = 2; nc = 2; mm3[0] = 11; mm3[1] = 12;              break;
  }
  const float* Wih = (Lw == 0) ? Wih0 : ((Lw == 1) ? Wih1 : Wih2);
  const float* Whh = (Lw == 0) ? Whh0 : ((Lw == 1) ? Whh1 : Whh2);
  const float* bih = (Lw == 0) ? bih0 : ((Lw == 1) ? bih1 : bih2);
  const float* bhh = (Lw == 0) ? bhh0 : ((Lw == 1) ? bhh1 : bhh2);
  const int lenih = (Lw == 0) ? 12 : 50;
  const int nkc   = (Lw == 0) ? 2 : 4;

  // ---- per-cell weight fragments, biases, write offsets, c-state ----
  half8  af[3][4];
  floatx4 bia[3];
  float  cst[3] = {0.f, 0.f, 0.f};
  int    woA[3], woB[3];
  bool   uokk[3];
#pragma unroll
  for (int i = 0; i < 3; ++i) {
    bia[i] = (floatx4){0, 0, 0, 0};
#pragma unroll
    for (int kc = 0; kc < 4; ++kc) af[i][kc] = (half8){};
    int m = mm3[i];
    int u = 4 * m + q;
    int uc = (u < 50) ? u : 49;
    uokk[i] = (i < nc) && (u < 50);
    if (Lw == 0) { woA[i] = offA0 (n, 12 + uc); woB[i] = offA12(n, uc); }
    else         { woA[i] = offA12(n, 50 + uc); woB[i] = offA12(n, uc); }
    if (i < nc) {
      int R = 16 * m + n;
#pragma unroll
      for (int kc = 0; kc < 4; ++kc)
        if (kc < nkc)
          af[i][kc] = wfrag(Wih, Whh, lenih, lenih, R, kc * 32 + q * 8);
      if (u < 50) {
#pragma unroll
        for (int g = 0; g < 4; ++g) {
          float sc = (g == 2) ? 2.885390082f : -1.442695041f;
          bia[i][g] = sc * (bih[g * 50 + u] + bhh[g * 50 + u]);
        }
      }
    }
  }

  // ---- lane-constant LDS read offsets (halfs) ----
  const int ro0[2] = { offA0(n, q * 8), offA0(n, 32 + q * 8) };
  const int ro1[4] = { offA12(n, q * 8),      offA12(n, 32 + q * 8),
                       offA12(n, 64 + q * 8), offA12(n, 96 + q * 8) };

  // ---- x stager: tid<192 = waves 0..2 (L0 waves), 16 rows x 12 feats ----
  const int sr = (tid < 192) ? tid / 12 : 0;
  const int sf = (tid < 192) ? tid - sr * 12 : 0;
  const int sxo = offA0(sr, sf);
  const float* xp = x + ((size_t)(blk * BT + sr) * Tt) * 12 + sf;
  float xnext = 0.f;

  __syncthreads();   // zero-fill visible
  if (tid < 192) {
    sm.act0[0][sxo] = (_Float16)xp[0];   // x(0) into parity-0 buffer
    xnext = xp[12];                      // x(1)
  }
  __syncthreads();

  // Tick TAU (parity p): read planes [p], write planes [1-p]. L0 does step
  // TAU (active TAU<=335), L1 step TAU-1 (1<=TAU<=336), L2 step TAU-2
  // (2<=TAU<=337). CHK=1 -> literal-TAU activity checks (fill/drain folds).
#define TICK(p, TAU, CHK)                                                  \
  {                                                                        \
    if (Lw == 0) {                                                         \
      if (!(CHK) || (TAU) <= 335) {                                        \
        half8 b0 = *(const half8*)&sm.act0[p][ro0[0]];                     \
        half8 b1 = *(const half8*)&sm.act0[p][ro0[1]];                     \
        for (int i = 0; i < 3; ++i) if (i < nc) {                          \
          floatx4 z = bia[i];                                              \
          z = MFMA(af[i][0], b0, z);                                       \
          z = MFMA(af[i][1], b1, z);                                       \
          float h = lstm_cell(z, cst[i]);                                  \
          _Float16 hh = (_Float16)h;                                       \
          if (uokk[i]) { sm.act0[1 - (p)][woA[i]] = hh;                    \
                         sm.act1[1 - (p)][woB[i]] = hh; }                  \
        }                                                                  \
      }                                                                    \
    } else if (Lw == 1) {                                                  \
      if (!(CHK) || ((TAU) >= 1 && (TAU) <= 336)) {                        \
        half8 b0 = *(const half8*)&sm.act1[p][ro1[0]];                     \
        half8 b1 = *(const half8*)&sm.act1[p][ro1[1]];                     \
        half8 b2 = *(const half8*)&sm.act1[p][ro1[2]];                     \
        half8 b3 = *(const half8*)&sm.act1[p][ro1[3]];                     \
        for (int i = 0; i < 3; ++i) if (i < nc) {                          \
          floatx4 z = bia[i];                                              \
          z = MFMA(af[i][0], b0, z);                                       \
          z = MFMA(af[i][1], b1, z);                                       \
          z = MFMA(af[i][2], b2, z);                                       \
          z = MFMA(af[i][3], b3, z);                                       \
          float h = lstm_cell(z, cst[i]);                                  \
          _Float16 hh = (_Float16)h;                                       \
          if (uokk[i]) { sm.act1[1 - (p)][woA[i]] = hh;                    \
                         sm.act2[1 - (p)][woB[i]] = hh; }                  \
        }                                                                  \
      }                                                                    \
    } else {                                                               \
      if (!(CHK) || ((TAU) >= 2)) {                                        \
        half8 b0 = *(const half8*)&sm.act2[p][ro1[0]];                     \
        half8 b1 = *(const half8*)&sm.act2[p][ro1[1]];                     \
        half8 b2 = *(const half8*)&sm.act2[p][ro1[2]];                     \
        half8 b3 = *(const half8*)&sm.act2[p][ro1[3]];                     \
        for (int i = 0; i < 3; ++i) if (i < nc) {                          \
          floatx4 z = bia[i];                                              \
          z = MFMA(af[i][0], b0, z);                                       \
          z = MFMA(af[i][1], b1, z);                                       \
          z = MFMA(af[i][2], b2, z);                                       \
          z = MFMA(af[i][3], b3, z);                                       \
          float h = lstm_cell(z, cst[i]);                                  \
          if (uokk[i]) sm.act2[1 - (p)][woA[i]] = (_Float16)h;             \
        }                                                                  \
      }                                                                    \
    }                                                                      \
    if (tid < 192) {                                                       \
      if ((TAU) + 1 < Tt) sm.act0[1 - (p)][sxo] = (_Float16)xnext;         \
      xnext = ((TAU) + 2 < Tt) ? xp[((TAU) + 2) * 12] : 0.f;               \
    }                                                                      \
    __syncthreads();                                                       \
  }

  // fill (literal TAU -> activity folds at compile time)
  TICK(0, 0, 1)
  TICK(1, 1, 1)
  // steady: ticks 2..335 (334 ticks, unroll-2 for literal parity)
#pragma unroll 1
  for (int t = 2; t < Tt; t += 2) {
    TICK(0, t, 0)
    TICK(1, t + 1, 0)
  }
  // drain
  TICK(0, 336, 1)
  TICK(1, 337, 1)
#undef TICK

  // ---- epilogue: out[r] = b_lin + h2(335) . W_lin ----
  // L2 step 335 ran at tick 337 (p=1) -> wrote act2[0]
  if (tid < BT) {
    float s = blin[0];
    for (int uu = 0; uu < 50; ++uu)
      s += Wlin[uu] * (float)sm.act2[0][offA12(tid, 50 + uu)];
    out[blk * BT + tid] = s;
  }
}

extern "C" void kernel_launch(void* const* d_in, const int* in_sizes, int n_in,
                              void* d_out, int out_size, void* d_ws, size_t ws_size,
                              hipStream_t stream) {
  const float* x    = (const float*)d_in[0];
  const float* Wih0 = (const float*)d_in[1];
  const float* Whh0 = (const float*)d_in[2];
  const float* bih0 = (const float*)d_in[3];
  const float* bhh0 = (const float*)d_in[4];
  const float* Wih1 = (const float*)d_in[5];
  const float* Whh1 = (const float*)d_in[6];
  const float* bih1 = (const float*)d_in[7];
  const float* bhh1 = (const float*)d_in[8];
  const float* Wih2 = (const float*)d_in[9];
  const float* Whh2 = (const float*)d_in[10];
  const float* bih2 = (const float*)d_in[11];
  const float* bhh2 = (const float*)d_in[12];
  const float* Wlin = (const float*)d_in[13];
  const float* blin = (const float*)d_in[14];
  float* outp = (float*)d_out;

  dim3 grid(Bsz / BT);   // 256 blocks, 1 per CU
  dim3 block(NTH);       // 16 waves -> 4 per SIMD
  lstm_mfma_kernel<<<grid, block, 0, stream>>>(
      x, Wih0, Whh0, bih0, bhh0, Wih1, Whh1, bih1, bhh1,
      Wih2, Whh2, bih2, bhh2, Wlin, blin, outp);
}